// Round 10
// baseline (87.027 us; speedup 1.0000x reference)
//
#include <hip/hip_runtime.h>

// DeformableConv2D round 14: r12 geometry, 8-wave blocks via phase-B SPLIT-K.
//
// r13 post-mortem: flat -- merging 2 blocks into one 8-wave block kept total
// waves at 3584 (448x8 = 896x4); per-CU available work unchanged, so nothing
// improved. r12's counters (Occ 20.7% = 6.6 waves/CU avg, VALUBusy 18%, main
// ~31us vs ~5us issue-time estimate) say ~80% of main is stalled on the
// per-tap chain (ds_read_b128 ~120cy -> blend -> MFMA) with too few
// independent waves to hide it.
//
// This round doubles the wave count instead: PW=14, 896 blocks, but 512
// threads; wave = (sh, g) where sh = K-half (ch 0-31 / 32-63), g = group.
//   * phase B per wave per tap: 4 corner b128 reads + 32-fma blend + 1 MFMA
//     (half of r12's); partial accB summed via 4KB LDS buffer at the end
//     (f32 add, same as MFMA-internal accumulation -> absmax unchanged).
//   * total waves 3584 -> 7168 (28/CU of work); LDS 33.5KB -> 4 blocks/CU;
//     launch_bounds(512,8) caps VGPR at 64 so all 32 waves/CU are eligible
//     (phase-B working set ~50 VGPR -- no r5-style load serialization).
//   * phase A: waves 0-4 each one N-tile (unified oc<80 path, offkt rows
//     72-79 are zero-padded; offb read guarded); waves 5-7 idle through A.
// Barriers per block: 4.
//
// MFMA 16x16x32 f16 layouts (verified by earlier passing runs):
//   A-frag: lane holds A[m=lane&15][k=(lane>>4)*8+j]
//   B-frag: lane holds B[k=(lane>>4)*8+j][n=lane&15]   (B stored [n][k])
//   C/D  : col(n)=lane&15, row(m)=(lane>>4)*4+reg

#define NH 56
#define NW 56
#define NC 64
#define NDG 4
#define NK 9
#define NOFF 72
#define NOFFP 80
#define NF 64
#define KTOT 576
#define HWPIX 3136
#define NPIX 12544

#define PW    14            // pixels per block (one row segment; 4 segs/row)
#define WR    5             // window rows  (oh-2 .. oh+2)
#define WC    18            // window cols  (ow0-2 .. ow0+15)
#define WPOS  (WR * WC)     // 90 positions
#define NBLK  (4 * NH * 4)  // 896

#define WS_OFFKT 0          // f16 [80][576]   = 92160 B
#define WS_WK    92160      // f16 [9][64][64] = 73728 B

typedef _Float16 half8   __attribute__((ext_vector_type(8)));
typedef _Float16 half4   __attribute__((ext_vector_type(4)));
typedef float    floatx4 __attribute__((ext_vector_type(4)));

// ---------------- prep: weight conversion ----------------
__global__ __launch_bounds__(256)
void dcn_prep(const float* __restrict__ offk,   // [3,3,64,72] (kk,oc)
              const float* __restrict__ wk,     // [3,3,64,64] (k,f,c)
              _Float16* __restrict__ offkt,     // [80][576]   (oc,kk)
              _Float16* __restrict__ wkh)       // [9][64][64]
{
    const int i = blockIdx.x * 256 + threadIdx.x;
    if (i < NOFFP * KTOT) {
        const int oc = i / KTOT;
        const int kk = i - oc * KTOT;
        const float v = (oc < NOFF) ? offk[kk * NOFF + oc] : 0.0f;
        offkt[i] = (_Float16)v;
    }
    const int j = i - NOFFP * KTOT;
    if (j >= 0 && j < NK * NF * NC) wkh[j] = (_Float16)wk[j];
}

// f16 window swizzle (16B granules contiguous; spread banks across pos)
__device__ __forceinline__ int winh_idx(int pos, int c) {     // elem units
    return (pos << 6) + (c ^ ((pos & 7) << 3));
}

// ---------------- fused main ----------------
__global__ __launch_bounds__(512, 8)
void dcn_main(const float* __restrict__ x,        // [4,56,56,64]
              const _Float16* __restrict__ offkt, // [80][576]
              const float* __restrict__ offb,     // [72]
              const _Float16* __restrict__ wkh,   // [9][64][64]
              float* __restrict__ out)            // [12544][64]
{
    __shared__ __align__(16) _Float16 s_winh[WPOS * NC];    // 11520 B
    __shared__ float s_off[PW * NOFF];                      // 4032 B
    __shared__ __align__(16) float s_cww[36 * 16 * 4];      // 9216 B  [k*4+g][p]
    __shared__ __align__(8)  unsigned s_cwl[36 * 16 * 2];   // 4608 B  [k*4+g][p]
    __shared__ __align__(16) float s_red[4 * 64 * 4];       // 4096 B
    // total 33472 B -> 4 blocks/CU

    const int tid  = threadIdx.x;
    const int wid  = tid >> 6;      // 0..7
    const int g    = wid & 3;       // deformable group (phase B)
    const int sh   = wid >> 2;      // K-half (phase B)
    const int lane = tid & 63;
    const int m    = lane & 15;     // MFMA row / col index
    const int kq   = lane >> 4;     // MFMA k-quad
    const int kq8  = kq * 8;

    // block -> (b, oh, ow0)
    const int blk = blockIdx.x;
    const int b   = blk / (NH * 4);
    const int r2  = blk - b * (NH * 4);
    const int oh  = r2 >> 2;
    const int ow0 = (r2 & 3) * PW;
    const int bb  = b * HWPIX;

    // ---- stage window (f16), zero-padded outside image ----
    for (int i = tid; i < WPOS * 16; i += 512) {
        const int pos = i >> 4;
        const int g4  = (i & 15) * 4;
        const int ry  = pos / WC;
        const int rx  = pos - ry * WC;
        const int iy  = oh + ry - 2;
        const int ix  = ow0 + rx - 2;
        float4 v = make_float4(0.f, 0.f, 0.f, 0.f);
        if ((unsigned)iy < NH && (unsigned)ix < NW)
            v = *(const float4*)&x[(size_t)((bb + iy * NW + ix) * NC) + g4];
        half4 h;
        h[0] = (_Float16)v.x; h[1] = (_Float16)v.y;
        h[2] = (_Float16)v.z; h[3] = (_Float16)v.w;
        *(half4*)&s_winh[winh_idx(pos, g4)] = h;
    }
    __syncthreads();

    // ---- phase A: offset conv GEMM, waves 0..4 (one N-tile each) ----
    if (wid < 5) {
        const int oc0 = wid * 16 + m;   // 0..79; rows 72..79 of offkt are zero
        floatx4 acc;
        { const float bv = (oc0 < NOFF) ? offb[oc0] : 0.0f;
          acc = (floatx4){bv, bv, bv, bv}; }
        #pragma unroll
        for (int k = 0; k < NK; ++k) {
            const int ki = k / 3, kj = k - 3 * ki;
            const int pos = (ki + 1) * WC + (m + kj + 1);   // m>=PW: masked
            #pragma unroll
            for (int s2 = 0; s2 < 2; ++s2) {
                const half8 af = *(const half8*)&s_winh[winh_idx(pos, s2 * 32 + kq8)];
                const int kkb = k * 64 + s2 * 32 + kq8;
                const half8 bf = *(const half8*)&offkt[(size_t)oc0 * KTOT + kkb];
                acc = __builtin_amdgcn_mfma_f32_16x16x32_f16(af, bf, acc, 0, 0, 0);
            }
        }
        if (oc0 < NOFF) {
            #pragma unroll
            for (int r = 0; r < 4; ++r) {
                const int row = kq * 4 + r;
                if (row < PW)
                    s_off[row * NOFF + oc0] = acc[r];
            }
        }
    }
    __syncthreads();

    // ---- phase A': coord/weight table, slot = (k*4+g)*16 + p ----
    for (int i = tid; i < 36 * 16; i += 512) {
        const int kg = i >> 4;                  // k*NDG + g
        const int p  = i & 15;
        float4 wv = make_float4(0.f, 0.f, 0.f, 0.f);
        unsigned c0 = 0, c1 = 0;                // pad slots: pos 0, weight 0
        if (p < PW) {
            const int k  = kg >> 2;
            const int ki = k / 3, kj = k - 3 * ki;
            const int ow = ow0 + p;
            const float offy = s_off[p * NOFF + kg * 2 + 0];
            const float offx = s_off[p * NOFF + kg * 2 + 1];
            float yv = fminf(fmaxf((float)(oh + ki) + offy, 0.0f), 57.0f);
            float xv = fminf(fmaxf((float)(ow + kj) + offx, 0.0f), 57.0f);
            const float y0f = floorf(yv), x0f = floorf(xv);
            const int y0 = (int)y0f, x0 = (int)x0f;
            const int y1 = min(y0 + 1, 57), x1 = min(x0 + 1, 57);
            const float ly = yv - y0f,       lx = xv - x0f;
            const float hy = (float)y1 - yv, hx = (float)x1 - xv;
            const bool vy0 = (unsigned)(y0 - 1) < NH;
            const bool vy1 = (unsigned)(y1 - 1) < NH;
            const bool vx0 = (unsigned)(x0 - 1) < NW;
            const bool vx1 = (unsigned)(x1 - 1) < NW;
            wv = make_float4((vy0 && vx0) ? hy * hx : 0.0f,
                             (vy0 && vx1) ? hy * lx : 0.0f,
                             (vy1 && vx0) ? ly * hx : 0.0f,
                             (vy1 && vx1) ? ly * lx : 0.0f);
            const int y0c = min(max(y0 - 1, 0), NH - 1);
            const int y1c = min(max(y1 - 1, 0), NH - 1);
            const int x0c = min(max(x0 - 1, 0), NW - 1);
            const int x1c = min(max(x1 - 1, 0), NW - 1);
            const int ry0 = y0c - oh + 2, ry1 = y1c - oh + 2;
            const int rx0 = x0c - ow0 + 2, rx1 = x1c - ow0 + 2;
            if ((unsigned)ry0 < WR && (unsigned)ry1 < WR &&
                (unsigned)rx0 < WC && (unsigned)rx1 < WC) {
                c0 = (unsigned)(ry0 * WC + rx0) | ((unsigned)(ry0 * WC + rx1) << 16);
                c1 = (unsigned)(ry1 * WC + rx0) | ((unsigned)(ry1 * WC + rx1) << 16);
            } else {                            // rare: packed clamped coords
                c0 = 0x80000000u | ((unsigned)y0c << 18) | ((unsigned)x0c << 12)
                   | ((unsigned)y1c << 6) | (unsigned)x1c;
                c1 = c0;
            }
        }
        *(float4*)&s_cww[i * 4] = wv;
        s_cwl[i * 2 + 0] = c0;
        s_cwl[i * 2 + 1] = c1;
    }
    __syncthreads();

    // ---- phase B: split-K sampling + grouped conv ----
    floatx4 accB = (floatx4){0.f, 0.f, 0.f, 0.f};
    const int sofs = sh * 32;                   // this wave's channel half
    const int tb = g * 16 + m;                  // table slot (pixel m, group g)
    float4   cw = *(const float4*)&s_cww[tb * 4];
    unsigned c0 = s_cwl[tb * 2 + 0];
    unsigned c1 = s_cwl[tb * 2 + 1];
    #pragma unroll 1
    for (int k = 0; k < NK; ++k) {
        const int tn = (k + 1 < NK ? k + 1 : k) * 64 + tb;
        const float4   cwn = *(const float4*)&s_cww[tn * 4];
        const unsigned c0n = s_cwl[tn * 2 + 0];
        const unsigned c1n = s_cwl[tn * 2 + 1];

        const half8 bf = *(const half8*)&wkh[(size_t)(k * NF + g * 16 + m) * NC +
                                             sofs + kq8];

        half8 q00, q01, q10, q11;               // 4 corners, 8 f16 each
        if (__builtin_expect((c0 & 0x80000000u) == 0, 1)) {
            const int p00 = c0 & 0xFFFF, p01 = c0 >> 16;
            const int p10 = c1 & 0xFFFF, p11 = c1 >> 16;
            const int cc = sofs + kq8;
            q00 = *(const half8*)&s_winh[winh_idx(p00, cc)];
            q01 = *(const half8*)&s_winh[winh_idx(p01, cc)];
            q10 = *(const half8*)&s_winh[winh_idx(p10, cc)];
            q11 = *(const half8*)&s_winh[winh_idx(p11, cc)];
        } else {
            const int y0c = (c0 >> 18) & 63, x0c = (c0 >> 12) & 63;
            const int y1c = (c0 >> 6) & 63,  x1c = c0 & 63;
            const int i00 = (bb + y0c * NW + x0c) * NC + sofs + kq8;
            const int i01 = (bb + y0c * NW + x1c) * NC + sofs + kq8;
            const int i10 = (bb + y1c * NW + x0c) * NC + sofs + kq8;
            const int i11 = (bb + y1c * NW + x1c) * NC + sofs + kq8;
            #pragma unroll
            for (int j = 0; j < 8; ++j) {
                q00[j] = (_Float16)x[i00 + j];
                q01[j] = (_Float16)x[i01 + j];
                q10[j] = (_Float16)x[i10 + j];
                q11[j] = (_Float16)x[i11 + j];
            }
        }

        half8 af;
        #pragma unroll
        for (int j = 0; j < 8; ++j) {
            float v = cw.x * (float)q00[j];         // v_fma_mix_f32 chain
            v = fmaf(cw.y, (float)q01[j], v);
            v = fmaf(cw.z, (float)q10[j], v);
            v = fmaf(cw.w, (float)q11[j], v);
            af[j] = (_Float16)v;
        }
        accB = __builtin_amdgcn_mfma_f32_16x16x32_f16(af, bf, accB, 0, 0, 0);
        cw = cwn; c0 = c0n; c1 = c1n;
    }

    // ---- reduce K-halves and store ----
    if (sh == 1)
        *(floatx4*)&s_red[(g * 64 + lane) * 4] = accB;
    __syncthreads();
    if (sh == 0) {
        const floatx4 o = *(const floatx4*)&s_red[(g * 64 + lane) * 4];
        accB += o;
        #pragma unroll
        for (int r = 0; r < 4; ++r) {
            const int row = kq * 4 + r;
            if (row < PW)
                out[(size_t)(bb + oh * NW + ow0 + row) * NF + g * 16 + m] = accB[r];
        }
    }
}

extern "C" void kernel_launch(void* const* d_in, const int* in_sizes, int n_in,
                              void* d_out, int out_size, void* d_ws, size_t ws_size,
                              hipStream_t stream) {
    const float* xin  = (const float*)d_in[0];
    const float* offk = (const float*)d_in[1];
    const float* offb = (const float*)d_in[2];
    const float* wk   = (const float*)d_in[3];
    float* outp = (float*)d_out;

    _Float16* offkt = (_Float16*)((char*)d_ws + WS_OFFKT);
    _Float16* wkh   = (_Float16*)((char*)d_ws + WS_WK);

    dcn_prep<<<324, 256, 0, stream>>>(offk, wk, offkt, wkh);
    dcn_main<<<NBLK, 512, 0, stream>>>(xin, offkt, offb, wkh, outp);
}

// Round 12
// 85.517 us; speedup vs baseline: 1.0177x; 1.0177x over previous
//
#include <hip/hip_runtime.h>

// DeformableConv2D round 16: r12 base + BRANCHLESS phase-B window path +
// full tap unroll (the r11 pipeline, minus the branch that killed it).
//
// r15 post-mortem: two-kernel split REVERTED -- pre-check passed (0.0156) but
// post-timing diverged reproducibly (1.92): call-count-dependent hazard around
// the cross-kernel goff handoff under graph replay. Unlocalizable; r12 is the
// trusted base.
//
// r11 lesson: the per-tap chain (table read -> 8 corner ds_reads ~120cy ->
// blend -> MFMA) never pipelined because the divergent fallback branch sat in
// the dataflow. This round makes the window path branchless:
//   * fallback slots store pos=0 in c0/c1 (benign LDS reads, REAL weights) and
//     move their packed clamped coords to a 3rd table s_cwf (u32, 0 = none).
//   * phase B always window-reads + blends; rare `if (cf)` fixup OVERWRITES
//     af0/af1 from global afterward (execz-skipped in practice).
//   * tap loop fully unrolled: static slot offsets let the compiler hoist
//     tap k+1's table+corner reads above tap k's blend (cross-tap pipeline).
// Numerics identical to r12 (same weights, same f16-corner f32-accum blend,
// same fixup math) -> absmax should stay 0.015625.
//
// LDS: s_winh 11520 + s_off 4032 + s_cww 9216 + s_cwl 4608 + s_cwf 2304
//    = 31680 B. Barriers per block: 3.
//
// MFMA 16x16x32 f16 layouts (verified by earlier passing runs):
//   A-frag: lane holds A[m=lane&15][k=(lane>>4)*8+j]
//   B-frag: lane holds B[k=(lane>>4)*8+j][n=lane&15]   (B stored [n][k])
//   C/D  : col(n)=lane&15, row(m)=(lane>>4)*4+reg

#define NH 56
#define NW 56
#define NC 64
#define NDG 4
#define NK 9
#define NOFF 72
#define NOFFP 80
#define NF 64
#define KTOT 576
#define HWPIX 3136
#define NPIX 12544

#define PW    14            // pixels per block (one row segment; 4 segs/row)
#define WR    5             // window rows  (oh-2 .. oh+2)
#define WC    18            // window cols  (ow0-2 .. ow0+15)
#define WPOS  (WR * WC)     // 90 positions
#define NBLK  (4 * NH * 4)  // 896

#define WS_OFFKT 0          // f16 [80][576]   = 92160 B
#define WS_WK    92160      // f16 [9][64][64] = 73728 B

typedef _Float16 half8   __attribute__((ext_vector_type(8)));
typedef _Float16 half4   __attribute__((ext_vector_type(4)));
typedef float    floatx4 __attribute__((ext_vector_type(4)));

// ---------------- prep: weight conversion ----------------
__global__ __launch_bounds__(256)
void dcn_prep(const float* __restrict__ offk,   // [3,3,64,72] (kk,oc)
              const float* __restrict__ wk,     // [3,3,64,64] (k,f,c)
              _Float16* __restrict__ offkt,     // [80][576]   (oc,kk)
              _Float16* __restrict__ wkh)       // [9][64][64]
{
    const int i = blockIdx.x * 256 + threadIdx.x;
    if (i < NOFFP * KTOT) {
        const int oc = i / KTOT;
        const int kk = i - oc * KTOT;
        const float v = (oc < NOFF) ? offk[kk * NOFF + oc] : 0.0f;
        offkt[i] = (_Float16)v;
    }
    const int j = i - NOFFP * KTOT;
    if (j >= 0 && j < NK * NF * NC) wkh[j] = (_Float16)wk[j];
}

// f16 window swizzle (16B granules contiguous; spread banks across pos)
__device__ __forceinline__ int winh_idx(int pos, int c) {     // elem units
    return (pos << 6) + (c ^ ((pos & 7) << 3));
}

// ---------------- fused main ----------------
__global__ __launch_bounds__(256, 4)
void dcn_main(const float* __restrict__ x,        // [4,56,56,64]
              const _Float16* __restrict__ offkt, // [80][576]
              const float* __restrict__ offb,     // [72]
              const _Float16* __restrict__ wkh,   // [9][64][64]
              float* __restrict__ out)            // [12544][64]
{
    __shared__ __align__(16) _Float16 s_winh[WPOS * NC];    // 11520 B
    __shared__ float s_off[PW * NOFF];                      // 4032 B
    __shared__ __align__(16) float s_cww[36 * 16 * 4];      // 9216 B  [k*4+g][p]
    __shared__ __align__(8)  unsigned s_cwl[36 * 16 * 2];   // 4608 B  [k*4+g][p]
    __shared__ unsigned s_cwf[36 * 16];                     // 2304 B  fallback

    const int tid  = threadIdx.x;
    const int w    = tid >> 6;      // wave id: A = N-tile, B = group
    const int lane = tid & 63;
    const int m    = lane & 15;     // MFMA row / col index
    const int kq   = lane >> 4;     // MFMA k-quad
    const int kq8  = kq * 8;

    // block -> (b, oh, ow0)
    const int blk = blockIdx.x;
    const int b   = blk / (NH * 4);
    const int r2  = blk - b * (NH * 4);
    const int oh  = r2 >> 2;
    const int ow0 = (r2 & 3) * PW;
    const int bb  = b * HWPIX;

    // ---- stage window (f16), zero-padded outside image ----
    for (int i = tid; i < WPOS * 16; i += 256) {
        const int pos = i >> 4;
        const int g4  = (i & 15) * 4;
        const int ry  = pos / WC;
        const int rx  = pos - ry * WC;
        const int iy  = oh + ry - 2;
        const int ix  = ow0 + rx - 2;
        float4 v = make_float4(0.f, 0.f, 0.f, 0.f);
        if ((unsigned)iy < NH && (unsigned)ix < NW)
            v = *(const float4*)&x[(size_t)((bb + iy * NW + ix) * NC) + g4];
        half4 h;
        h[0] = (_Float16)v.x; h[1] = (_Float16)v.y;
        h[2] = (_Float16)v.z; h[3] = (_Float16)v.w;
        *(half4*)&s_winh[winh_idx(pos, g4)] = h;
    }
    __syncthreads();

    // ---- phase A: offset conv GEMM from f16 window ----
    const int oc0 = w * 16 + m;     // 0..63
    floatx4 acc0, acc1;
    { const float bv = offb[oc0]; acc0 = (floatx4){bv, bv, bv, bv}; }
    { const float bv = (w == 3 && m < 8) ? offb[64 + m] : 0.0f;
      acc1 = (floatx4){bv, bv, bv, bv}; }

    #pragma unroll
    for (int k = 0; k < NK; ++k) {
        const int ki = k / 3, kj = k - 3 * ki;
        const int pos = (ki + 1) * WC + (m + kj + 1);   // m>=PW: garbage, masked
        #pragma unroll
        for (int s = 0; s < 2; ++s) {
            const half8 af = *(const half8*)&s_winh[winh_idx(pos, s * 32 + kq8)];
            const int kkb = k * 64 + s * 32 + kq8;
            const half8 bf0 = *(const half8*)&offkt[(size_t)oc0 * KTOT + kkb];
            acc0 = __builtin_amdgcn_mfma_f32_16x16x32_f16(af, bf0, acc0, 0, 0, 0);
            if (w == 3) {
                const half8 bf1 = *(const half8*)&offkt[(size_t)(64 + m) * KTOT + kkb];
                acc1 = __builtin_amdgcn_mfma_f32_16x16x32_f16(af, bf1, acc1, 0, 0, 0);
            }
        }
    }
    #pragma unroll
    for (int r = 0; r < 4; ++r)
        if (kq * 4 + r < PW)
            s_off[(kq * 4 + r) * NOFF + oc0] = acc0[r];
    if (w == 3 && m < 8) {
        #pragma unroll
        for (int r = 0; r < 4; ++r)
            if (kq * 4 + r < PW)
                s_off[(kq * 4 + r) * NOFF + 64 + m] = acc1[r];
    }
    __syncthreads();

    // ---- phase A': coord/weight table, slot = (k*4+g)*16 + p ----
    for (int i = tid; i < 36 * 16; i += 256) {
        const int kg = i >> 4;                  // k*NDG + g
        const int p  = i & 15;
        float4 wv = make_float4(0.f, 0.f, 0.f, 0.f);
        unsigned c0 = 0, c1 = 0, cfv = 0;       // pad slots: pos 0, weight 0
        if (p < PW) {
            const int k  = kg >> 2;
            const int ki = k / 3, kj = k - 3 * ki;
            const int ow = ow0 + p;
            const float offy = s_off[p * NOFF + kg * 2 + 0];
            const float offx = s_off[p * NOFF + kg * 2 + 1];
            float yv = fminf(fmaxf((float)(oh + ki) + offy, 0.0f), 57.0f);
            float xv = fminf(fmaxf((float)(ow + kj) + offx, 0.0f), 57.0f);
            const float y0f = floorf(yv), x0f = floorf(xv);
            const int y0 = (int)y0f, x0 = (int)x0f;
            const int y1 = min(y0 + 1, 57), x1 = min(x0 + 1, 57);
            const float ly = yv - y0f,       lx = xv - x0f;
            const float hy = (float)y1 - yv, hx = (float)x1 - xv;
            const bool vy0 = (unsigned)(y0 - 1) < NH;
            const bool vy1 = (unsigned)(y1 - 1) < NH;
            const bool vx0 = (unsigned)(x0 - 1) < NW;
            const bool vx1 = (unsigned)(x1 - 1) < NW;
            wv = make_float4((vy0 && vx0) ? hy * hx : 0.0f,
                             (vy0 && vx1) ? hy * lx : 0.0f,
                             (vy1 && vx0) ? ly * hx : 0.0f,
                             (vy1 && vx1) ? ly * lx : 0.0f);
            const int y0c = min(max(y0 - 1, 0), NH - 1);
            const int y1c = min(max(y1 - 1, 0), NH - 1);
            const int x0c = min(max(x0 - 1, 0), NW - 1);
            const int x1c = min(max(x1 - 1, 0), NW - 1);
            const int ry0 = y0c - oh + 2, ry1 = y1c - oh + 2;
            const int rx0 = x0c - ow0 + 2, rx1 = x1c - ow0 + 2;
            if ((unsigned)ry0 < WR && (unsigned)ry1 < WR &&
                (unsigned)rx0 < WC && (unsigned)rx1 < WC) {
                c0 = (unsigned)(ry0 * WC + rx0) | ((unsigned)(ry0 * WC + rx1) << 16);
                c1 = (unsigned)(ry1 * WC + rx0) | ((unsigned)(ry1 * WC + rx1) << 16);
            } else {                            // rare: coords to s_cwf; pos 0
                cfv = 0x80000000u | ((unsigned)y0c << 18) | ((unsigned)x0c << 12)
                    | ((unsigned)y1c << 6) | (unsigned)x1c;
            }
        }
        *(float4*)&s_cww[i * 4] = wv;
        s_cwl[i * 2 + 0] = c0;
        s_cwl[i * 2 + 1] = c1;
        s_cwf[i] = cfv;
    }
    __syncthreads();

    // ---- phase B: branchless window path, full unroll, rare fixup ----
    floatx4 accB = (floatx4){0.f, 0.f, 0.f, 0.f};
    const int tb = w * 16 + m;                  // table slot (pixel m, group w)
    #pragma unroll
    for (int k = 0; k < NK; ++k) {
        const int sl = k * 64 + tb;
        const float4   cw = *(const float4*)&s_cww[sl * 4];
        const unsigned c0 = s_cwl[sl * 2 + 0];
        const unsigned c1 = s_cwl[sl * 2 + 1];
        const unsigned cf = s_cwf[sl];

        const _Float16* wp = &wkh[(size_t)(k * NF + w * 16 + m) * NC];
        const half8 bf0 = *(const half8*)&wp[kq8];
        const half8 bf1 = *(const half8*)&wp[32 + kq8];

        // always-on window reads (fallback slots read pos 0: benign)
        const int p00 = c0 & 0xFFFF, p01 = c0 >> 16;
        const int p10 = c1 & 0xFFFF, p11 = c1 >> 16;
        const int ca = kq8, cb = 32 + kq8;
        const half8 q00a = *(const half8*)&s_winh[winh_idx(p00, ca)];
        const half8 q01a = *(const half8*)&s_winh[winh_idx(p01, ca)];
        const half8 q10a = *(const half8*)&s_winh[winh_idx(p10, ca)];
        const half8 q11a = *(const half8*)&s_winh[winh_idx(p11, ca)];
        const half8 q00b = *(const half8*)&s_winh[winh_idx(p00, cb)];
        const half8 q01b = *(const half8*)&s_winh[winh_idx(p01, cb)];
        const half8 q10b = *(const half8*)&s_winh[winh_idx(p10, cb)];
        const half8 q11b = *(const half8*)&s_winh[winh_idx(p11, cb)];

        half8 af0, af1;
        #pragma unroll
        for (int j = 0; j < 8; ++j) {
            float v0 = cw.x * (float)q00a[j];       // v_fma_mix_f32 chain
            v0 = fmaf(cw.y, (float)q01a[j], v0);
            v0 = fmaf(cw.z, (float)q10a[j], v0);
            v0 = fmaf(cw.w, (float)q11a[j], v0);
            af0[j] = (_Float16)v0;
            float v1 = cw.x * (float)q00b[j];
            v1 = fmaf(cw.y, (float)q01b[j], v1);
            v1 = fmaf(cw.z, (float)q10b[j], v1);
            v1 = fmaf(cw.w, (float)q11b[j], v1);
            af1[j] = (_Float16)v1;
        }

        if (__builtin_expect(cf != 0, 0)) {     // rare fixup: overwrite af
            const int y0c = (cf >> 18) & 63, x0c = (cf >> 12) & 63;
            const int y1c = (cf >> 6) & 63,  x1c = cf & 63;
            const int i00 = (bb + y0c * NW + x0c) * NC;
            const int i01 = (bb + y0c * NW + x1c) * NC;
            const int i10 = (bb + y1c * NW + x0c) * NC;
            const int i11 = (bb + y1c * NW + x1c) * NC;
            #pragma unroll
            for (int j = 0; j < 8; ++j) {
                float v0 = cw.x * (float)(_Float16)x[i00 + kq8 + j];
                v0 = fmaf(cw.y, (float)(_Float16)x[i01 + kq8 + j], v0);
                v0 = fmaf(cw.z, (float)(_Float16)x[i10 + kq8 + j], v0);
                v0 = fmaf(cw.w, (float)(_Float16)x[i11 + kq8 + j], v0);
                af0[j] = (_Float16)v0;
                float v1 = cw.x * (float)(_Float16)x[i00 + 32 + kq8 + j];
                v1 = fmaf(cw.y, (float)(_Float16)x[i01 + 32 + kq8 + j], v1);
                v1 = fmaf(cw.z, (float)(_Float16)x[i10 + 32 + kq8 + j], v1);
                v1 = fmaf(cw.w, (float)(_Float16)x[i11 + 32 + kq8 + j], v1);
                af1[j] = (_Float16)v1;
            }
        }

        accB = __builtin_amdgcn_mfma_f32_16x16x32_f16(af0, bf0, accB, 0, 0, 0);
        accB = __builtin_amdgcn_mfma_f32_16x16x32_f16(af1, bf1, accB, 0, 0, 0);
    }

    #pragma unroll
    for (int r = 0; r < 4; ++r) {
        const int row = kq * 4 + r;
        if (row < PW)
            out[(size_t)(bb + oh * NW + ow0 + row) * NF + w * 16 + m] = accB[r];
    }
}

extern "C" void kernel_launch(void* const* d_in, const int* in_sizes, int n_in,
                              void* d_out, int out_size, void* d_ws, size_t ws_size,
                              hipStream_t stream) {
    const float* xin  = (const float*)d_in[0];
    const float* offk = (const float*)d_in[1];
    const float* offb = (const float*)d_in[2];
    const float* wk   = (const float*)d_in[3];
    float* outp = (float*)d_out;

    _Float16* offkt = (_Float16*)((char*)d_ws + WS_OFFKT);
    _Float16* wkh   = (_Float16*)((char*)d_ws + WS_WK);

    dcn_prep<<<324, 256, 0, stream>>>(offk, wk, offkt, wkh);
    dcn_main<<<NBLK, 256, 0, stream>>>(xin, offkt, offb, wkh, outp);
}